// Round 1
// baseline (237.041 us; speedup 1.0000x reference)
//
#include <hip/hip_runtime.h>

// Problem constants
constexpr int Bb  = 16;
constexpr int CDD = 10;
constexpr int Lc  = 64;
constexpr int T   = 128;
constexpr int H   = 768;
constexpr int NH  = 12;
constexpr int DH  = 64;    // H/NH
constexpr int S   = 768;   // CDD*Lc + T
constexpr int SQ  = 640;   // CDD*Lc
constexpr int MROWS = Bb * S;  // 12288

typedef __attribute__((ext_vector_type(8))) short bf16x8;
typedef __attribute__((ext_vector_type(4))) short bf16x4;
typedef __attribute__((ext_vector_type(4))) float f32x4;

__device__ inline unsigned short f2bf(float f) {
  unsigned u = __float_as_uint(f);
  u += 0x7fff + ((u >> 16) & 1);   // RNE
  return (unsigned short)(u >> 16);
}
__device__ inline float bf2f(unsigned short h) {
  return __uint_as_float(((unsigned)h) << 16);
}

__device__ inline void gld_lds16(const void* g, void* l) {
  __builtin_amdgcn_global_load_lds(
      (const __attribute__((address_space(1))) void*)g,
      (__attribute__((address_space(3))) void*)l, 16, 0, 0);
}

__device__ inline bf16x8 ld_b64x2(const unsigned short* p) {
  union { bf16x8 v; bf16x4 h[2]; } u;
  u.h[0] = *(const bf16x4*)p;
  u.h[1] = *(const bf16x4*)(p + 4);
  return u.v;
}

// ---------------- fp32 -> bf16 convert ----------------
__global__ void convert_bf16(const float* __restrict__ in,
                             unsigned short* __restrict__ out, int n4) {
  int i = blockIdx.x * blockDim.x + threadIdx.x;
  int stride = gridDim.x * blockDim.x;
  for (; i < n4; i += stride) {
    float4 v = ((const float4*)in)[i];
    ushort4 o;
    o.x = f2bf(v.x); o.y = f2bf(v.y); o.z = f2bf(v.z); o.w = f2bf(v.w);
    ((ushort4*)out)[i] = o;
  }
}

// ---------------- QKV projection GEMM: Y = X * W^T + bias ----------------
// M=12288, N=768, K=768.  128x128 tile, BK=32, 4 waves of 64x64.
// z picks {Q,K,V}. For z==2 (V), rows with s>=640 also go to d_out (fp32).
__launch_bounds__(256, 2)
__global__ void qkv_gemm(const unsigned short* __restrict__ Xb,
                         const unsigned short* __restrict__ Wb,
                         const float* __restrict__ bq, const float* __restrict__ bk,
                         const float* __restrict__ bv,
                         unsigned short* __restrict__ Qb, unsigned short* __restrict__ Kb,
                         unsigned short* __restrict__ Vb,
                         float* __restrict__ out) {
  const int z = blockIdx.z;
  const unsigned short* W = Wb + (size_t)z * H * H;
  const float* bias = (z == 0) ? bq : (z == 1) ? bk : bv;
  unsigned short* Y = (z == 0) ? Qb : (z == 1) ? Kb : Vb;

  const int i0 = blockIdx.x * 128;
  const int j0 = blockIdx.y * 128;
  const int tid = threadIdx.x;
  const int wave = tid >> 6, lane = tid & 63;
  const int wr = wave >> 1, wc = wave & 1;
  const int col = lane & 15, quad = lane >> 4;

  // row stride 32 elems (4 chunks of 8 bf16); chunk swizzle ^((row>>1)&3)
  __shared__ unsigned short As[128 * 32];
  __shared__ unsigned short Bs[128 * 32];

  f32x4 acc[4][4];
#pragma unroll
  for (int i = 0; i < 4; i++)
#pragma unroll
    for (int j = 0; j < 4; j++) acc[i][j] = (f32x4){0.f, 0.f, 0.f, 0.f};

  const int rowA0 = tid >> 2, csA0 = tid & 3;
  const int rowA1 = (tid + 256) >> 2, csA1 = tid & 3;  // (tid+256)&3 == tid&3
  const int gcA0 = csA0 ^ ((rowA0 >> 1) & 3);
  const int gcA1 = csA1 ^ ((rowA1 >> 1) & 3);

  for (int kt = 0; kt < 24; kt++) {
    const int k0 = kt * 32;
    gld_lds16(Xb + (size_t)(i0 + rowA0) * H + k0 + gcA0 * 8, &As[tid * 8]);
    gld_lds16(Xb + (size_t)(i0 + rowA1) * H + k0 + gcA1 * 8, &As[(tid + 256) * 8]);
    gld_lds16(W  + (size_t)(j0 + rowA0) * H + k0 + gcA0 * 8, &Bs[tid * 8]);
    gld_lds16(W  + (size_t)(j0 + rowA1) * H + k0 + gcA1 * 8, &Bs[(tid + 256) * 8]);
    __builtin_amdgcn_s_waitcnt(0);
    __syncthreads();

    bf16x8 a[4], b[4];
#pragma unroll
    for (int mt = 0; mt < 4; mt++) {
      int r = wr * 64 + mt * 16 + col;
      a[mt] = *(const bf16x8*)&As[r * 32 + ((quad ^ ((r >> 1) & 3)) * 8)];
    }
#pragma unroll
    for (int nt = 0; nt < 4; nt++) {
      int r = wc * 64 + nt * 16 + col;
      b[nt] = *(const bf16x8*)&Bs[r * 32 + ((quad ^ ((r >> 1) & 3)) * 8)];
    }
#pragma unroll
    for (int mt = 0; mt < 4; mt++)
#pragma unroll
      for (int nt = 0; nt < 4; nt++)
        acc[mt][nt] = __builtin_amdgcn_mfma_f32_16x16x32_bf16(a[mt], b[nt], acc[mt][nt], 0, 0, 0);
    __syncthreads();
  }

#pragma unroll
  for (int mt = 0; mt < 4; mt++) {
#pragma unroll
    for (int nt = 0; nt < 4; nt++) {
      const int j = j0 + wc * 64 + nt * 16 + col;
      const float bj = bias[j];
#pragma unroll
      for (int r = 0; r < 4; r++) {
        const int i = i0 + wr * 64 + mt * 16 + quad * 4 + r;
        const float v = acc[mt][nt][r] + bj;
        Y[(size_t)i * H + j] = f2bf(v);
        if (z == 2) {
          int s = i - (i / S) * S;
          if (s >= SQ) out[(size_t)i * H + j] = v;  // tail rows: out = V row
        }
      }
    }
  }
}

// ---------------- V column totals: Vtot[b][j] = sum_s V[b,s,j] ----------------
__global__ void vtot_kernel(const unsigned short* __restrict__ Vb,
                            float* __restrict__ Vtot) {
  const int b = blockIdx.x;
  const int j = blockIdx.y * 256 + threadIdx.x;
  float s = 0.f;
  for (int r = 0; r < S; r++) s += bf2f(Vb[(size_t)(b * S + r) * H + j]);
  Vtot[b * H + j] = s;
}

// ---------------- fused masked attention ----------------
// One block per (b, h, chunk c). 192 live keys = chunk(64) + tail(128).
// Masked keys have score exactly 0 (multiplicative mask), handled in closed form:
//   m = max(0, max live s);  Z = sum live e^(s-m) + 576 e^-m
//   ctx = (sum live e^(s-m) v + e^-m (Vtot - sum staged v)) / Z
__launch_bounds__(256, 2)
__global__ void attn_kernel(const unsigned short* __restrict__ Qb,
                            const unsigned short* __restrict__ Kb,
                            const unsigned short* __restrict__ Vb,
                            const float* __restrict__ Vtot,
                            float* __restrict__ out) {
  const int bid = blockIdx.x;
  const int c = bid % CDD;
  const int h = (bid / CDD) % NH;
  const int b = bid / (CDD * NH);
  const int tid = threadIdx.x;
  const int wave = tid >> 6, lane = tid & 63;
  const int col = lane & 15, quad = lane >> 4;

  __shared__ __align__(16) char smem[59136];
  unsigned short* Qs = (unsigned short*)smem;            // 64x64 (stride 64, swizzled), 8KB
  unsigned short* Ks = (unsigned short*)(smem + 8192);   // 192x64 (stride 64, swizzled), 24KB
  unsigned short* Ps = (unsigned short*)smem;            // 64 x stride196 bf16 (aliases Qs+Ks)
  unsigned short* Vt = (unsigned short*)(smem + 32768);  // 64 x stride196 (V transposed)
  float* red   = (float*)(smem + 57856);                 // 256 f
  float* vcorr = (float*)(smem + 58880);                 // 64 f

  const size_t rowQ0 = (size_t)(b * S + c * 64) * H + h * DH;

  // --- stage Q (512 slots), K (1536 slots) via global_load_lds, swizzle ^(row&7)
  {
    int s0 = tid, s1 = tid + 256;
    int r0 = s0 >> 3, g0 = (s0 & 7) ^ (r0 & 7);
    int r1 = s1 >> 3, g1 = (s1 & 7) ^ (r1 & 7);
    gld_lds16(Qb + rowQ0 + (size_t)r0 * H + g0 * 8, &Qs[s0 * 8]);
    gld_lds16(Qb + rowQ0 + (size_t)r1 * H + g1 * 8, &Qs[s1 * 8]);
  }
#pragma unroll
  for (int j = 0; j < 6; j++) {
    int s = tid + 256 * j;
    int key = s >> 3;
    int gkey = (key < 64) ? (c * 64 + key) : (576 + key);
    int gc = (s & 7) ^ (key & 7);
    gld_lds16(Kb + (size_t)(b * S + gkey) * H + h * DH + gc * 8, &Ks[s * 8]);
  }
  // --- stage V transposed: Vt[d][key], stride 196 (196%8==4 breaks write conflicts)
#pragma unroll
  for (int j = 0; j < 6; j++) {
    int s = tid + 256 * j;
    int key = s >> 3;
    int f0 = (s & 7) * 8;
    int gkey = (key < 64) ? (c * 64 + key) : (576 + key);
    union { int4 i4; unsigned short u[8]; } uv;
    uv.i4 = *(const int4*)(Vb + (size_t)(b * S + gkey) * H + h * DH + f0);
#pragma unroll
    for (int i = 0; i < 8; i++) Vt[(f0 + i) * 196 + key] = uv.u[i];
  }
  __builtin_amdgcn_s_waitcnt(0);
  __syncthreads();

  // --- staged-V column sums (for the masked correction)
  {
    int d = tid & 63, p = tid >> 6;
    float sum = 0.f;
    for (int k = p * 48; k < p * 48 + 48; k++) sum += bf2f(Vt[d * 196 + k]);
    red[tid] = sum;
  }
  __syncthreads();
  if (tid < 64) {
    float tot = Vtot[b * H + h * DH + tid];
    vcorr[tid] = tot - (red[tid] + red[64 + tid] + red[128 + tid] + red[192 + tid]);
  }

  // --- QK^T: wave handles q-rows [wave*16, wave*16+16), 12 col-tiles, K=64
  f32x4 sc[12];
#pragma unroll
  for (int n = 0; n < 12; n++) sc[n] = (f32x4){0.f, 0.f, 0.f, 0.f};
  {
    const int rq = wave * 16 + col;
    bf16x8 a0 = *(const bf16x8*)&Qs[rq * 64 + ((quad ^ (rq & 7)) * 8)];
    bf16x8 a1 = *(const bf16x8*)&Qs[rq * 64 + (((4 + quad) ^ (rq & 7)) * 8)];
#pragma unroll
    for (int n = 0; n < 12; n++) {
      const int rk = n * 16 + col;
      bf16x8 b0 = *(const bf16x8*)&Ks[rk * 64 + ((quad ^ (rk & 7)) * 8)];
      bf16x8 b1 = *(const bf16x8*)&Ks[rk * 64 + (((4 + quad) ^ (rk & 7)) * 8)];
      sc[n] = __builtin_amdgcn_mfma_f32_16x16x32_bf16(a0, b0, sc[n], 0, 0, 0);
      sc[n] = __builtin_amdgcn_mfma_f32_16x16x32_bf16(a1, b1, sc[n], 0, 0, 0);
    }
  }

  // --- masked softmax (exact, multiplicative-mask semantics)
  float em[4], zin[4];
  {
    const float scale = 0.125f;  // 1/sqrt(64)
#pragma unroll
    for (int r = 0; r < 4; r++) {
      float mx = sc[0][r];
#pragma unroll
      for (int n = 1; n < 12; n++) mx = fmaxf(mx, sc[n][r]);
#pragma unroll
      for (int msk = 1; msk <= 8; msk <<= 1) mx = fmaxf(mx, __shfl_xor(mx, msk, 64));
      const float mrow = fmaxf(mx * scale, 0.f);
      float rs = 0.f;
#pragma unroll
      for (int n = 0; n < 12; n++) {
        float p = __expf(sc[n][r] * scale - mrow);
        sc[n][r] = p;
        rs += p;
      }
#pragma unroll
      for (int msk = 1; msk <= 8; msk <<= 1) rs += __shfl_xor(rs, msk, 64);
      const float e = __expf(-mrow);
      em[r] = e;
      zin[r] = 1.f / (rs + 576.f * e);
    }
  }
  __syncthreads();  // all Qs/Ks reads done before Ps (aliased) writes; vcorr visible

  // --- P -> LDS (bf16, stride 196)
#pragma unroll
  for (int n = 0; n < 12; n++)
#pragma unroll
    for (int r = 0; r < 4; r++)
      Ps[(wave * 16 + quad * 4 + r) * 196 + n * 16 + col] = f2bf(sc[n][r]);
  __syncthreads();

  // --- PV: wave rows [wave*16,+16) x 64 cols, K=192
  f32x4 o[4];
#pragma unroll
  for (int n2 = 0; n2 < 4; n2++) o[n2] = (f32x4){0.f, 0.f, 0.f, 0.f};
#pragma unroll
  for (int ks = 0; ks < 6; ks++) {
    bf16x8 a = ld_b64x2(&Ps[(wave * 16 + col) * 196 + ks * 32 + quad * 8]);
#pragma unroll
    for (int n2 = 0; n2 < 4; n2++) {
      bf16x8 bvv = ld_b64x2(&Vt[(n2 * 16 + col) * 196 + ks * 32 + quad * 8]);
      o[n2] = __builtin_amdgcn_mfma_f32_16x16x32_bf16(a, bvv, o[n2], 0, 0, 0);
    }
  }

  // --- epilogue: add masked-V correction, normalize, store fp32
#pragma unroll
  for (int n2 = 0; n2 < 4; n2++) {
    const int d = n2 * 16 + col;
    const float vc = vcorr[d];
#pragma unroll
    for (int r = 0; r < 4; r++) {
      const int m = wave * 16 + quad * 4 + r;
      const float val = (o[n2][r] + em[r] * vc) * zin[r];
      out[(size_t)(b * S + c * 64 + m) * H + h * DH + d] = val;
    }
  }
}

extern "C" void kernel_launch(void* const* d_in, const int* in_sizes, int n_in,
                              void* d_out, int out_size, void* d_ws, size_t ws_size,
                              hipStream_t stream) {
  const float* X  = (const float*)d_in[0];
  const float* Wq = (const float*)d_in[1];
  const float* bq = (const float*)d_in[2];
  const float* Wk = (const float*)d_in[3];
  const float* bk = (const float*)d_in[4];
  const float* Wv = (const float*)d_in[5];
  const float* bv = (const float*)d_in[6];
  float* out = (float*)d_out;

  char* ws = (char*)d_ws;
  // workspace layout (75.4 MB total)
  unsigned short* Xb   = (unsigned short*)ws;                    // 12288x768 bf16
  unsigned short* Wb   = (unsigned short*)(ws + 18874368);       // 3x768x768 bf16
  unsigned short* Qb   = (unsigned short*)(ws + 22413312);       // 12288x768 bf16
  unsigned short* Kb   = (unsigned short*)(ws + 41287680);
  unsigned short* Vb   = (unsigned short*)(ws + 60162048);
  float*          Vt   = (float*)(ws + 79036416);                // 16x768 f32

  convert_bf16<<<2048, 256, 0, stream>>>(X, Xb, MROWS * H / 4);
  convert_bf16<<<576, 256, 0, stream>>>(Wq, Wb, H * H / 4);
  convert_bf16<<<576, 256, 0, stream>>>(Wk, Wb + H * H, H * H / 4);
  convert_bf16<<<576, 256, 0, stream>>>(Wv, Wb + 2 * H * H, H * H / 4);

  qkv_gemm<<<dim3(96, 6, 3), 256, 0, stream>>>(Xb, Wb, bq, bk, bv, Qb, Kb, Vb, out);
  vtot_kernel<<<dim3(16, 3), 256, 0, stream>>>(Vb, Vt);
  attn_kernel<<<1920, 256, 0, stream>>>(Qb, Kb, Vb, Vt, out);
}

// Round 2
// 193.419 us; speedup vs baseline: 1.2255x; 1.2255x over previous
//
#include <hip/hip_runtime.h>

// Problem constants
constexpr int Bb  = 16;
constexpr int CDD = 10;
constexpr int Lc  = 64;
constexpr int T   = 128;
constexpr int H   = 768;
constexpr int NH  = 12;
constexpr int DH  = 64;    // H/NH
constexpr int S   = 768;   // CDD*Lc + T
constexpr int SQ  = 640;   // CDD*Lc
constexpr int MROWS = Bb * S;  // 12288

typedef __attribute__((ext_vector_type(8))) short bf16x8;
typedef __attribute__((ext_vector_type(4))) short bf16x4;
typedef __attribute__((ext_vector_type(4))) float f32x4;

__device__ inline unsigned short f2bf(float f) {
  unsigned u = __float_as_uint(f);
  u += 0x7fff + ((u >> 16) & 1);   // RNE
  return (unsigned short)(u >> 16);
}
__device__ inline float bf2f(unsigned short h) {
  return __uint_as_float(((unsigned)h) << 16);
}

__device__ inline void gld_lds16(const void* g, void* l) {
  __builtin_amdgcn_global_load_lds(
      (const __attribute__((address_space(1))) void*)g,
      (__attribute__((address_space(3))) void*)l, 16, 0, 0);
}

__device__ inline bf16x8 ld_b64x2(const unsigned short* p) {
  union { bf16x8 v; bf16x4 h[2]; } u;
  u.h[0] = *(const bf16x4*)p;
  u.h[1] = *(const bf16x4*)(p + 4);
  return u.v;
}

// ---------------- fp32 -> bf16 convert (X + 3 weights, one launch) ------------
constexpr int NX4 = MROWS * H / 4;   // 2359296 float4s
constexpr int NW4 = H * H / 4;       // 147456 float4s
__global__ void convert_all(const float* __restrict__ X,
                            const float* __restrict__ Wq,
                            const float* __restrict__ Wk,
                            const float* __restrict__ Wv,
                            unsigned short* __restrict__ Xb,
                            unsigned short* __restrict__ Wb) {
  int i = blockIdx.x * blockDim.x + threadIdx.x;
  const int stride = gridDim.x * blockDim.x;
  const int total = NX4 + 3 * NW4;
  for (; i < total; i += stride) {
    const float* src;
    unsigned short* dst;
    int off;
    if (i < NX4) {
      src = X; dst = Xb; off = i;
    } else {
      int k = i - NX4;
      int w = k / NW4;
      off = k - w * NW4;
      src = (w == 0) ? Wq : (w == 1) ? Wk : Wv;
      dst = Wb + (size_t)w * H * H;
    }
    float4 v = ((const float4*)src)[off];
    ushort4 o;
    o.x = f2bf(v.x); o.y = f2bf(v.y); o.z = f2bf(v.z); o.w = f2bf(v.w);
    ((ushort4*)dst)[off] = o;
  }
}

// ---------------- QKV projection GEMM: Y = X * W^T + bias ----------------
// M=12288, N=768, K=768.  128x128 tile, BK=32, 4 waves of 64x64.
// z picks {Q,K,V}. For z==2 (V), rows with s>=640 also go to d_out (fp32).
// launch_bounds (256,4): 64 VGPR + 64 AGPR = 128 regs -> 4 waves/SIMD fits.
__launch_bounds__(256, 4)
__global__ void qkv_gemm(const unsigned short* __restrict__ Xb,
                         const unsigned short* __restrict__ Wb,
                         const float* __restrict__ bq, const float* __restrict__ bk,
                         const float* __restrict__ bv,
                         unsigned short* __restrict__ Qb, unsigned short* __restrict__ Kb,
                         unsigned short* __restrict__ Vb,
                         float* __restrict__ out) {
  const int z = blockIdx.z;
  const unsigned short* W = Wb + (size_t)z * H * H;
  const float* bias = (z == 0) ? bq : (z == 1) ? bk : bv;
  unsigned short* Y = (z == 0) ? Qb : (z == 1) ? Kb : Vb;

  const int i0 = blockIdx.x * 128;
  const int j0 = blockIdx.y * 128;
  const int tid = threadIdx.x;
  const int wave = tid >> 6, lane = tid & 63;
  const int wr = wave >> 1, wc = wave & 1;
  const int col = lane & 15, quad = lane >> 4;

  // row stride 32 elems (4 chunks of 8 bf16); chunk swizzle ^((row>>1)&3)
  __shared__ unsigned short As[128 * 32];
  __shared__ unsigned short Bs[128 * 32];

  f32x4 acc[4][4];
#pragma unroll
  for (int i = 0; i < 4; i++)
#pragma unroll
    for (int j = 0; j < 4; j++) acc[i][j] = (f32x4){0.f, 0.f, 0.f, 0.f};

  const int rowA0 = tid >> 2, csA0 = tid & 3;
  const int rowA1 = (tid + 256) >> 2, csA1 = tid & 3;  // (tid+256)&3 == tid&3
  const int gcA0 = csA0 ^ ((rowA0 >> 1) & 3);
  const int gcA1 = csA1 ^ ((rowA1 >> 1) & 3);

  for (int kt = 0; kt < 24; kt++) {
    const int k0 = kt * 32;
    gld_lds16(Xb + (size_t)(i0 + rowA0) * H + k0 + gcA0 * 8, &As[tid * 8]);
    gld_lds16(Xb + (size_t)(i0 + rowA1) * H + k0 + gcA1 * 8, &As[(tid + 256) * 8]);
    gld_lds16(W  + (size_t)(j0 + rowA0) * H + k0 + gcA0 * 8, &Bs[tid * 8]);
    gld_lds16(W  + (size_t)(j0 + rowA1) * H + k0 + gcA1 * 8, &Bs[(tid + 256) * 8]);
    __builtin_amdgcn_s_waitcnt(0);
    __syncthreads();

    bf16x8 a[4], b[4];
#pragma unroll
    for (int mt = 0; mt < 4; mt++) {
      int r = wr * 64 + mt * 16 + col;
      a[mt] = *(const bf16x8*)&As[r * 32 + ((quad ^ ((r >> 1) & 3)) * 8)];
    }
#pragma unroll
    for (int nt = 0; nt < 4; nt++) {
      int r = wc * 64 + nt * 16 + col;
      b[nt] = *(const bf16x8*)&Bs[r * 32 + ((quad ^ ((r >> 1) & 3)) * 8)];
    }
#pragma unroll
    for (int mt = 0; mt < 4; mt++)
#pragma unroll
      for (int nt = 0; nt < 4; nt++)
        acc[mt][nt] = __builtin_amdgcn_mfma_f32_16x16x32_bf16(a[mt], b[nt], acc[mt][nt], 0, 0, 0);
    __syncthreads();
  }

#pragma unroll
  for (int mt = 0; mt < 4; mt++) {
#pragma unroll
    for (int nt = 0; nt < 4; nt++) {
      const int j = j0 + wc * 64 + nt * 16 + col;
      const float bj = bias[j];
#pragma unroll
      for (int r = 0; r < 4; r++) {
        const int i = i0 + wr * 64 + mt * 16 + quad * 4 + r;
        const float v = acc[mt][nt][r] + bj;
        Y[(size_t)i * H + j] = f2bf(v);
        if (z == 2) {
          int s = i - (i / S) * S;
          if (s >= SQ) out[(size_t)i * H + j] = v;  // tail rows: out = V row
        }
      }
    }
  }
}

// ---------------- V column partial sums ----------------
// grid (16, 3, 8): b x 256-col tile x 96-row segment. 384 blocks.
// part[b][rs][j] = sum_{r in seg rs} V[b,r,j]; attn folds the 8 partials.
__global__ void vtot_partial(const unsigned short* __restrict__ Vb,
                             float* __restrict__ part) {
  const int b = blockIdx.x;
  const int j = blockIdx.y * 256 + threadIdx.x;
  const int rs = blockIdx.z;
  const unsigned short* p = Vb + (size_t)(b * S + rs * 96) * H + j;
  float s = 0.f;
#pragma unroll 8
  for (int r = 0; r < 96; r++) s += bf2f(p[(size_t)r * H]);
  part[(size_t)(b * 8 + rs) * H + j] = s;
}

// ---------------- fused masked attention ----------------
// One block per (b, h, chunk c). 192 live keys = chunk(64) + tail(128).
// Masked keys have score exactly 0 (multiplicative mask), handled in closed form:
//   m = max(0, max live s);  Z = sum live e^(s-m) + 576 e^-m
//   ctx = (sum live e^(s-m) v + e^-m (Vtot - sum staged v)) / Z
__launch_bounds__(256, 2)
__global__ void attn_kernel(const unsigned short* __restrict__ Qb,
                            const unsigned short* __restrict__ Kb,
                            const unsigned short* __restrict__ Vb,
                            const float* __restrict__ part,
                            float* __restrict__ out) {
  const int bid = blockIdx.x;
  const int c = bid % CDD;
  const int h = (bid / CDD) % NH;
  const int b = bid / (CDD * NH);
  const int tid = threadIdx.x;
  const int wave = tid >> 6, lane = tid & 63;
  const int col = lane & 15, quad = lane >> 4;

  __shared__ __align__(16) char smem[59136];
  unsigned short* Qs = (unsigned short*)smem;            // 64x64 (stride 64, swizzled), 8KB
  unsigned short* Ks = (unsigned short*)(smem + 8192);   // 192x64 (stride 64, swizzled), 24KB
  unsigned short* Ps = (unsigned short*)smem;            // 64 x stride196 bf16 (aliases Qs+Ks)
  unsigned short* Vt = (unsigned short*)(smem + 32768);  // 64 x stride196 (V transposed)
  float* red   = (float*)(smem + 57856);                 // 256 f
  float* vcorr = (float*)(smem + 58880);                 // 64 f

  const size_t rowQ0 = (size_t)(b * S + c * 64) * H + h * DH;

  // --- stage Q (512 slots), K (1536 slots) via global_load_lds, swizzle ^(row&7)
  {
    int s0 = tid, s1 = tid + 256;
    int r0 = s0 >> 3, g0 = (s0 & 7) ^ (r0 & 7);
    int r1 = s1 >> 3, g1 = (s1 & 7) ^ (r1 & 7);
    gld_lds16(Qb + rowQ0 + (size_t)r0 * H + g0 * 8, &Qs[s0 * 8]);
    gld_lds16(Qb + rowQ0 + (size_t)r1 * H + g1 * 8, &Qs[s1 * 8]);
  }
#pragma unroll
  for (int j = 0; j < 6; j++) {
    int s = tid + 256 * j;
    int key = s >> 3;
    int gkey = (key < 64) ? (c * 64 + key) : (576 + key);
    int gc = (s & 7) ^ (key & 7);
    gld_lds16(Kb + (size_t)(b * S + gkey) * H + h * DH + gc * 8, &Ks[s * 8]);
  }
  // --- stage V transposed: Vt[d][key], stride 196 (196%8==4 breaks write conflicts)
#pragma unroll
  for (int j = 0; j < 6; j++) {
    int s = tid + 256 * j;
    int key = s >> 3;
    int f0 = (s & 7) * 8;
    int gkey = (key < 64) ? (c * 64 + key) : (576 + key);
    union { int4 i4; unsigned short u[8]; } uv;
    uv.i4 = *(const int4*)(Vb + (size_t)(b * S + gkey) * H + h * DH + f0);
#pragma unroll
    for (int i = 0; i < 8; i++) Vt[(f0 + i) * 196 + key] = uv.u[i];
  }
  __builtin_amdgcn_s_waitcnt(0);
  __syncthreads();

  // --- staged-V column sums (for the masked correction)
  {
    int d = tid & 63, p = tid >> 6;
    float sum = 0.f;
    for (int k = p * 48; k < p * 48 + 48; k++) sum += bf2f(Vt[d * 196 + k]);
    red[tid] = sum;
  }
  __syncthreads();
  if (tid < 64) {
    float tot = 0.f;
#pragma unroll
    for (int rs = 0; rs < 8; rs++) tot += part[(size_t)(b * 8 + rs) * H + h * DH + tid];
    vcorr[tid] = tot - (red[tid] + red[64 + tid] + red[128 + tid] + red[192 + tid]);
  }

  // --- QK^T: wave handles q-rows [wave*16, wave*16+16), 12 col-tiles, K=64
  f32x4 sc[12];
#pragma unroll
  for (int n = 0; n < 12; n++) sc[n] = (f32x4){0.f, 0.f, 0.f, 0.f};
  {
    const int rq = wave * 16 + col;
    bf16x8 a0 = *(const bf16x8*)&Qs[rq * 64 + ((quad ^ (rq & 7)) * 8)];
    bf16x8 a1 = *(const bf16x8*)&Qs[rq * 64 + (((4 + quad) ^ (rq & 7)) * 8)];
#pragma unroll
    for (int n = 0; n < 12; n++) {
      const int rk = n * 16 + col;
      bf16x8 b0 = *(const bf16x8*)&Ks[rk * 64 + ((quad ^ (rk & 7)) * 8)];
      bf16x8 b1 = *(const bf16x8*)&Ks[rk * 64 + (((4 + quad) ^ (rk & 7)) * 8)];
      sc[n] = __builtin_amdgcn_mfma_f32_16x16x32_bf16(a0, b0, sc[n], 0, 0, 0);
      sc[n] = __builtin_amdgcn_mfma_f32_16x16x32_bf16(a1, b1, sc[n], 0, 0, 0);
    }
  }

  // --- masked softmax (exact, multiplicative-mask semantics)
  float em[4], zin[4];
  {
    const float scale = 0.125f;  // 1/sqrt(64)
#pragma unroll
    for (int r = 0; r < 4; r++) {
      float mx = sc[0][r];
#pragma unroll
      for (int n = 1; n < 12; n++) mx = fmaxf(mx, sc[n][r]);
#pragma unroll
      for (int msk = 1; msk <= 8; msk <<= 1) mx = fmaxf(mx, __shfl_xor(mx, msk, 64));
      const float mrow = fmaxf(mx * scale, 0.f);
      float rs = 0.f;
#pragma unroll
      for (int n = 0; n < 12; n++) {
        float p = __expf(sc[n][r] * scale - mrow);
        sc[n][r] = p;
        rs += p;
      }
#pragma unroll
      for (int msk = 1; msk <= 8; msk <<= 1) rs += __shfl_xor(rs, msk, 64);
      const float e = __expf(-mrow);
      em[r] = e;
      zin[r] = 1.f / (rs + 576.f * e);
    }
  }
  __syncthreads();  // all Qs/Ks reads done before Ps (aliased) writes; vcorr visible

  // --- P -> LDS (bf16, stride 196)
#pragma unroll
  for (int n = 0; n < 12; n++)
#pragma unroll
    for (int r = 0; r < 4; r++)
      Ps[(wave * 16 + quad * 4 + r) * 196 + n * 16 + col] = f2bf(sc[n][r]);
  __syncthreads();

  // --- PV: wave rows [wave*16,+16) x 64 cols, K=192
  f32x4 o[4];
#pragma unroll
  for (int n2 = 0; n2 < 4; n2++) o[n2] = (f32x4){0.f, 0.f, 0.f, 0.f};
#pragma unroll
  for (int ks = 0; ks < 6; ks++) {
    bf16x8 a = ld_b64x2(&Ps[(wave * 16 + col) * 196 + ks * 32 + quad * 8]);
#pragma unroll
    for (int n2 = 0; n2 < 4; n2++) {
      bf16x8 bvv = ld_b64x2(&Vt[(n2 * 16 + col) * 196 + ks * 32 + quad * 8]);
      o[n2] = __builtin_amdgcn_mfma_f32_16x16x32_bf16(a, bvv, o[n2], 0, 0, 0);
    }
  }

  // --- epilogue: add masked-V correction, normalize, store fp32
#pragma unroll
  for (int n2 = 0; n2 < 4; n2++) {
    const int d = n2 * 16 + col;
    const float vc = vcorr[d];
#pragma unroll
    for (int r = 0; r < 4; r++) {
      const int m = wave * 16 + quad * 4 + r;
      const float val = (o[n2][r] + em[r] * vc) * zin[r];
      out[(size_t)(b * S + c * 64 + m) * H + h * DH + d] = val;
    }
  }
}

extern "C" void kernel_launch(void* const* d_in, const int* in_sizes, int n_in,
                              void* d_out, int out_size, void* d_ws, size_t ws_size,
                              hipStream_t stream) {
  const float* X  = (const float*)d_in[0];
  const float* Wq = (const float*)d_in[1];
  const float* bq = (const float*)d_in[2];
  const float* Wk = (const float*)d_in[3];
  const float* bk = (const float*)d_in[4];
  const float* Wv = (const float*)d_in[5];
  const float* bv = (const float*)d_in[6];
  float* out = (float*)d_out;

  char* ws = (char*)d_ws;
  // workspace layout (~75.8 MB total)
  unsigned short* Xb   = (unsigned short*)ws;                    // 12288x768 bf16
  unsigned short* Wb   = (unsigned short*)(ws + 18874368);       // 3x768x768 bf16
  unsigned short* Qb   = (unsigned short*)(ws + 22413312);       // 12288x768 bf16
  unsigned short* Kb   = (unsigned short*)(ws + 41287680);
  unsigned short* Vb   = (unsigned short*)(ws + 60162048);
  float*          part = (float*)(ws + 79036416);                // 16x8x768 f32

  convert_all<<<2048, 256, 0, stream>>>(X, Wq, Wk, Wv, Xb, Wb);
  qkv_gemm<<<dim3(96, 6, 3), 256, 0, stream>>>(Xb, Wb, bq, bk, bv, Qb, Kb, Vb, out);
  vtot_partial<<<dim3(16, 3, 8), 256, 0, stream>>>(Vb, part);
  attn_kernel<<<1920, 256, 0, stream>>>(Qb, Kb, Vb, part, out);
}

// Round 3
// 181.636 us; speedup vs baseline: 1.3050x; 1.0649x over previous
//
#include <hip/hip_runtime.h>

// Problem constants
constexpr int Bb  = 16;
constexpr int CDD = 10;
constexpr int Lc  = 64;
constexpr int T   = 128;
constexpr int H   = 768;
constexpr int NH  = 12;
constexpr int DH  = 64;    // H/NH
constexpr int S   = 768;   // CDD*Lc + T
constexpr int SQ  = 640;   // CDD*Lc
constexpr int MROWS = Bb * S;  // 12288

typedef __attribute__((ext_vector_type(8))) short bf16x8;
typedef __attribute__((ext_vector_type(4))) short bf16x4;
typedef __attribute__((ext_vector_type(4))) float f32x4;

__device__ inline unsigned short f2bf(float f) {
  unsigned u = __float_as_uint(f);
  u += 0x7fff + ((u >> 16) & 1);   // RNE
  return (unsigned short)(u >> 16);
}
__device__ inline float bf2f(unsigned short h) {
  return __uint_as_float(((unsigned)h) << 16);
}

__device__ inline void gld_lds16(const void* g, void* l) {
  __builtin_amdgcn_global_load_lds(
      (const __attribute__((address_space(1))) void*)g,
      (__attribute__((address_space(3))) void*)l, 16, 0, 0);
}

__device__ inline bf16x8 ld_b64x2(const unsigned short* p) {
  union { bf16x8 v; bf16x4 h[2]; } u;
  u.h[0] = *(const bf16x4*)p;
  u.h[1] = *(const bf16x4*)(p + 4);
  return u.v;
}

// ---------------- fp32 -> bf16 convert (X + 3 weights, one launch) ------------
constexpr int NX4 = MROWS * H / 4;   // 2359296 float4s
constexpr int NW4 = H * H / 4;       // 147456 float4s
__global__ void convert_all(const float* __restrict__ X,
                            const float* __restrict__ Wq,
                            const float* __restrict__ Wk,
                            const float* __restrict__ Wv,
                            unsigned short* __restrict__ Xb,
                            unsigned short* __restrict__ Wb) {
  int i = blockIdx.x * blockDim.x + threadIdx.x;
  const int stride = gridDim.x * blockDim.x;
  const int total = NX4 + 3 * NW4;
  for (; i < total; i += stride) {
    const float* src;
    unsigned short* dst;
    int off;
    if (i < NX4) {
      src = X; dst = Xb; off = i;
    } else {
      int k = i - NX4;
      int w = k / NW4;
      off = k - w * NW4;
      src = (w == 0) ? Wq : (w == 1) ? Wk : Wv;
      dst = Wb + (size_t)w * H * H;
    }
    float4 v = ((const float4*)src)[i < NX4 ? off : off];
    ushort4 o;
    o.x = f2bf(v.x); o.y = f2bf(v.y); o.z = f2bf(v.z); o.w = f2bf(v.w);
    ((ushort4*)dst)[off] = o;
  }
}

// ---------------- QKV projection GEMM: Y = X * W^T + bias ----------------
// M=12288, N=768, K=768.  128x128 tile, BK=64 (12 iters), 4 waves of 64x64.
// z picks {Q,K,V}. z==2 (V): tail rows (s>=640) also go to d_out (fp32), and
// V column sums are atomically accumulated into part[b][j] (vcorr input).
// z==0 (Q): pure-tail row tiles (blockIdx.x%6==5) are skipped - never read.
__launch_bounds__(256, 4)
__global__ void qkv_gemm(const unsigned short* __restrict__ Xb,
                         const unsigned short* __restrict__ Wb,
                         const float* __restrict__ bq, const float* __restrict__ bk,
                         const float* __restrict__ bv,
                         unsigned short* __restrict__ Qb, unsigned short* __restrict__ Kb,
                         unsigned short* __restrict__ Vb,
                         float* __restrict__ part,
                         float* __restrict__ out) {
  const int z = blockIdx.z;
  if (z == 0 && (blockIdx.x % 6) == 5) return;  // Q tail rows never consumed
  const unsigned short* W = Wb + (size_t)z * H * H;
  const float* bias = (z == 0) ? bq : (z == 1) ? bk : bv;
  unsigned short* Y = (z == 0) ? Qb : (z == 1) ? Kb : Vb;

  const int i0 = blockIdx.x * 128;
  const int j0 = blockIdx.y * 128;
  const int tid = threadIdx.x;
  const int wave = tid >> 6, lane = tid & 63;
  const int wr = wave >> 1, wc = wave & 1;
  const int col = lane & 15, quad = lane >> 4;

  // row stride 64 elems (8 chunks of 8 bf16); chunk swizzle ^(row&7)
  __shared__ unsigned short As[128 * 64];
  __shared__ unsigned short Bs[128 * 64];

  f32x4 acc[4][4];
#pragma unroll
  for (int i = 0; i < 4; i++)
#pragma unroll
    for (int j = 0; j < 4; j++) acc[i][j] = (f32x4){0.f, 0.f, 0.f, 0.f};

  // staging: thread handles slots tid+256*i (i=0..3); slot s -> row s>>3,
  // stored chunk s&7 holds global chunk (s&7)^(row&7)
  int rS[4], gcS[4];
#pragma unroll
  for (int i = 0; i < 4; i++) {
    int s = tid + 256 * i;
    rS[i] = s >> 3;
    gcS[i] = (s & 7) ^ (rS[i] & 7);
  }

  for (int kt = 0; kt < 12; kt++) {
    const int k0 = kt * 64;
#pragma unroll
    for (int i = 0; i < 4; i++)
      gld_lds16(Xb + (size_t)(i0 + rS[i]) * H + k0 + gcS[i] * 8, &As[(tid + 256 * i) * 8]);
#pragma unroll
    for (int i = 0; i < 4; i++)
      gld_lds16(W + (size_t)(j0 + rS[i]) * H + k0 + gcS[i] * 8, &Bs[(tid + 256 * i) * 8]);
    __builtin_amdgcn_s_waitcnt(0);
    __syncthreads();

#pragma unroll
    for (int h = 0; h < 2; h++) {
      bf16x8 a[4], b[4];
#pragma unroll
      for (int mt = 0; mt < 4; mt++) {
        int r = wr * 64 + mt * 16 + col;
        a[mt] = *(const bf16x8*)&As[r * 64 + (((h * 4 + quad) ^ (r & 7)) * 8)];
      }
#pragma unroll
      for (int nt = 0; nt < 4; nt++) {
        int r = wc * 64 + nt * 16 + col;
        b[nt] = *(const bf16x8*)&Bs[r * 64 + (((h * 4 + quad) ^ (r & 7)) * 8)];
      }
#pragma unroll
      for (int mt = 0; mt < 4; mt++)
#pragma unroll
        for (int nt = 0; nt < 4; nt++)
          acc[mt][nt] = __builtin_amdgcn_mfma_f32_16x16x32_bf16(a[mt], b[nt], acc[mt][nt], 0, 0, 0);
    }
    __syncthreads();
  }

  float colsum[4] = {0.f, 0.f, 0.f, 0.f};
#pragma unroll
  for (int mt = 0; mt < 4; mt++) {
#pragma unroll
    for (int nt = 0; nt < 4; nt++) {
      const int j = j0 + wc * 64 + nt * 16 + col;
      const float bj = bias[j];
#pragma unroll
      for (int r = 0; r < 4; r++) {
        const int i = i0 + wr * 64 + mt * 16 + quad * 4 + r;
        const float v = acc[mt][nt][r] + bj;
        Y[(size_t)i * H + j] = f2bf(v);
        if (z == 2) {
          colsum[nt] += v;
          int s = i - (i / S) * S;
          if (s >= SQ) out[(size_t)i * H + j] = v;  // tail rows: out = V row
        }
      }
    }
  }
  if (z == 2) {
    // wave covers 64 rows of one batch b; reduce over quad -> column sum
    const int b = blockIdx.x / 6;
#pragma unroll
    for (int nt = 0; nt < 4; nt++) {
      float s = colsum[nt];
      s += __shfl_xor(s, 16, 64);
      s += __shfl_xor(s, 32, 64);
      if (quad == 0) {
        const int j = j0 + wc * 64 + nt * 16 + col;
        atomicAdd(&part[b * H + j], s);
      }
    }
  }
}

// ---------------- fused masked attention ----------------
// One block per (b, h, chunk c). 192 live keys = chunk(64) + tail(128).
// Masked keys have score exactly 0 (multiplicative mask), handled in closed form:
//   m = max(0, max live s);  Z = sum live e^(s-m) + 576 e^-m
//   ctx = (sum live e^(s-m) v + e^-m (Vtot - sum staged v)) / Z
__launch_bounds__(256, 2)
__global__ void attn_kernel(const unsigned short* __restrict__ Qb,
                            const unsigned short* __restrict__ Kb,
                            const unsigned short* __restrict__ Vb,
                            const float* __restrict__ part,
                            float* __restrict__ out) {
  const int bid = blockIdx.x;
  const int c = bid % CDD;
  const int h = (bid / CDD) % NH;
  const int b = bid / (CDD * NH);
  const int tid = threadIdx.x;
  const int wave = tid >> 6, lane = tid & 63;
  const int col = lane & 15, quad = lane >> 4;

  __shared__ __align__(16) char smem[59136];
  unsigned short* Qs = (unsigned short*)smem;            // 64x64 (stride 64, swizzled), 8KB
  unsigned short* Ks = (unsigned short*)(smem + 8192);   // 192x64 (stride 64, swizzled), 24KB
  unsigned short* Ps = (unsigned short*)smem;            // 64 x stride196 bf16 (aliases Qs+Ks)
  unsigned short* Vt = (unsigned short*)(smem + 32768);  // 64 x stride196 (V transposed)
  float* red   = (float*)(smem + 57856);                 // 256 f
  float* vcorr = (float*)(smem + 58880);                 // 64 f

  const size_t rowQ0 = (size_t)(b * S + c * 64) * H + h * DH;

  // --- stage Q (512 slots), K (1536 slots) via global_load_lds, swizzle ^(row&7)
  {
    int s0 = tid, s1 = tid + 256;
    int r0 = s0 >> 3, g0 = (s0 & 7) ^ (r0 & 7);
    int r1 = s1 >> 3, g1 = (s1 & 7) ^ (r1 & 7);
    gld_lds16(Qb + rowQ0 + (size_t)r0 * H + g0 * 8, &Qs[s0 * 8]);
    gld_lds16(Qb + rowQ0 + (size_t)r1 * H + g1 * 8, &Qs[s1 * 8]);
  }
#pragma unroll
  for (int j = 0; j < 6; j++) {
    int s = tid + 256 * j;
    int key = s >> 3;
    int gkey = (key < 64) ? (c * 64 + key) : (576 + key);
    int gc = (s & 7) ^ (key & 7);
    gld_lds16(Kb + (size_t)(b * S + gkey) * H + h * DH + gc * 8, &Ks[s * 8]);
  }
  // --- stage V transposed: Vt[d][key], stride 196 (196%8==4 breaks write conflicts)
#pragma unroll
  for (int j = 0; j < 6; j++) {
    int s = tid + 256 * j;
    int key = s >> 3;
    int f0 = (s & 7) * 8;
    int gkey = (key < 64) ? (c * 64 + key) : (576 + key);
    union { int4 i4; unsigned short u[8]; } uv;
    uv.i4 = *(const int4*)(Vb + (size_t)(b * S + gkey) * H + h * DH + f0);
#pragma unroll
    for (int i = 0; i < 8; i++) Vt[(f0 + i) * 196 + key] = uv.u[i];
  }
  __builtin_amdgcn_s_waitcnt(0);
  __syncthreads();

  // --- staged-V column sums (for the masked correction)
  {
    int d = tid & 63, p = tid >> 6;
    float sum = 0.f;
    for (int k = p * 48; k < p * 48 + 48; k++) sum += bf2f(Vt[d * 196 + k]);
    red[tid] = sum;
  }
  __syncthreads();
  if (tid < 64) {
    float tot = part[b * H + h * DH + tid];
    vcorr[tid] = tot - (red[tid] + red[64 + tid] + red[128 + tid] + red[192 + tid]);
  }

  // --- QK^T: wave handles q-rows [wave*16, wave*16+16), 12 col-tiles, K=64
  f32x4 sc[12];
#pragma unroll
  for (int n = 0; n < 12; n++) sc[n] = (f32x4){0.f, 0.f, 0.f, 0.f};
  {
    const int rq = wave * 16 + col;
    bf16x8 a0 = *(const bf16x8*)&Qs[rq * 64 + ((quad ^ (rq & 7)) * 8)];
    bf16x8 a1 = *(const bf16x8*)&Qs[rq * 64 + (((4 + quad) ^ (rq & 7)) * 8)];
#pragma unroll
    for (int n = 0; n < 12; n++) {
      const int rk = n * 16 + col;
      bf16x8 b0 = *(const bf16x8*)&Ks[rk * 64 + ((quad ^ (rk & 7)) * 8)];
      bf16x8 b1 = *(const bf16x8*)&Ks[rk * 64 + (((4 + quad) ^ (rk & 7)) * 8)];
      sc[n] = __builtin_amdgcn_mfma_f32_16x16x32_bf16(a0, b0, sc[n], 0, 0, 0);
      sc[n] = __builtin_amdgcn_mfma_f32_16x16x32_bf16(a1, b1, sc[n], 0, 0, 0);
    }
  }

  // --- masked softmax (exact, multiplicative-mask semantics)
  float em[4], zin[4];
  {
    const float scale = 0.125f;  // 1/sqrt(64)
#pragma unroll
    for (int r = 0; r < 4; r++) {
      float mx = sc[0][r];
#pragma unroll
      for (int n = 1; n < 12; n++) mx = fmaxf(mx, sc[n][r]);
#pragma unroll
      for (int msk = 1; msk <= 8; msk <<= 1) mx = fmaxf(mx, __shfl_xor(mx, msk, 64));
      const float mrow = fmaxf(mx * scale, 0.f);
      float rs = 0.f;
#pragma unroll
      for (int n = 0; n < 12; n++) {
        float p = __expf(sc[n][r] * scale - mrow);
        sc[n][r] = p;
        rs += p;
      }
#pragma unroll
      for (int msk = 1; msk <= 8; msk <<= 1) rs += __shfl_xor(rs, msk, 64);
      const float e = __expf(-mrow);
      em[r] = e;
      zin[r] = 1.f / (rs + 576.f * e);
    }
  }
  __syncthreads();  // all Qs/Ks reads done before Ps (aliased) writes; vcorr visible

  // --- P -> LDS (bf16, stride 196)
#pragma unroll
  for (int n = 0; n < 12; n++)
#pragma unroll
    for (int r = 0; r < 4; r++)
      Ps[(wave * 16 + quad * 4 + r) * 196 + n * 16 + col] = f2bf(sc[n][r]);
  __syncthreads();

  // --- PV: wave rows [wave*16,+16) x 64 cols, K=192
  f32x4 o[4];
#pragma unroll
  for (int n2 = 0; n2 < 4; n2++) o[n2] = (f32x4){0.f, 0.f, 0.f, 0.f};
#pragma unroll
  for (int ks = 0; ks < 6; ks++) {
    bf16x8 a = ld_b64x2(&Ps[(wave * 16 + col) * 196 + ks * 32 + quad * 8]);
#pragma unroll
    for (int n2 = 0; n2 < 4; n2++) {
      bf16x8 bvv = ld_b64x2(&Vt[(n2 * 16 + col) * 196 + ks * 32 + quad * 8]);
      o[n2] = __builtin_amdgcn_mfma_f32_16x16x32_bf16(a, bvv, o[n2], 0, 0, 0);
    }
  }

  // --- epilogue: add masked-V correction, normalize, store fp32
#pragma unroll
  for (int n2 = 0; n2 < 4; n2++) {
    const int d = n2 * 16 + col;
    const float vc = vcorr[d];
#pragma unroll
    for (int r = 0; r < 4; r++) {
      const int m = wave * 16 + quad * 4 + r;
      const float val = (o[n2][r] + em[r] * vc) * zin[r];
      out[(size_t)(b * S + c * 64 + m) * H + h * DH + d] = val;
    }
  }
}

extern "C" void kernel_launch(void* const* d_in, const int* in_sizes, int n_in,
                              void* d_out, int out_size, void* d_ws, size_t ws_size,
                              hipStream_t stream) {
  const float* X  = (const float*)d_in[0];
  const float* Wq = (const float*)d_in[1];
  const float* bq = (const float*)d_in[2];
  const float* Wk = (const float*)d_in[3];
  const float* bk = (const float*)d_in[4];
  const float* Wv = (const float*)d_in[5];
  const float* bv = (const float*)d_in[6];
  float* out = (float*)d_out;

  char* ws = (char*)d_ws;
  // workspace layout (~75.5 MB total)
  unsigned short* Xb   = (unsigned short*)ws;                    // 12288x768 bf16
  unsigned short* Wb   = (unsigned short*)(ws + 18874368);       // 3x768x768 bf16
  unsigned short* Qb   = (unsigned short*)(ws + 22413312);       // 12288x768 bf16
  unsigned short* Kb   = (unsigned short*)(ws + 41287680);
  unsigned short* Vb   = (unsigned short*)(ws + 60162048);
  float*          part = (float*)(ws + 79036416);                // 16x768 f32 (atomic)

  hipMemsetAsync(part, 0, Bb * H * sizeof(float), stream);
  convert_all<<<2048, 256, 0, stream>>>(X, Wq, Wk, Wv, Xb, Wb);
  qkv_gemm<<<dim3(96, 6, 3), 256, 0, stream>>>(Xb, Wb, bq, bk, bv, Qb, Kb, Vb, part, out);
  attn_kernel<<<1920, 256, 0, stream>>>(Qb, Kb, Vb, part, out);
}